// Round 1
// baseline (1560.826 us; speedup 1.0000x reference)
//
#include <hip/hip_runtime.h>
#include <stdint.h>

#define NROWS 16384
#define NCODES 8192
#define DIM 256
#define GEMM_BM 64
#define GEMM_BN 256
#define GEMM_BK 16
#define CAP 32
#define MARGIN 1e-5f

// workspace layout (bytes)
#define OFF_C2F 0u           // float[8192]            32768
#define OFF_C2D 32768u       // double[8192]           65536
#define OFF_ROWPACK 98304u   // u64[16384]            131072
#define OFF_CNT 229376u      // u32[16384]             65536
#define OFF_CIDX 294912u     // u32[16384][CAP]      2097152
#define OFF_FIDX 2392064u    // u32[16384]             65536
#define OFF_LOSS 2457600u    // double[1]

__device__ __forceinline__ uint32_t enc_f32(float f) {
  uint32_t u = __float_as_uint(f);
  return (u & 0x80000000u) ? ~u : (u | 0x80000000u);
}
__device__ __forceinline__ float dec_f32(uint32_t e) {
  uint32_t b = (e & 0x80000000u) ? (e & 0x7fffffffu) : ~e;
  return __uint_as_float(b);
}

// ---- kernel 1: per-code squared norms (fp32 for scoring, fp64 for refine) ----
__global__ __launch_bounds__(256) void k_c2(const float* __restrict__ cb,
                                            float* __restrict__ c2f,
                                            double* __restrict__ c2d) {
  int j = blockIdx.x * 256 + threadIdx.x;
  if (j >= NCODES) return;
  const float* row = cb + (size_t)j * DIM;
  double s = 0.0;
  for (int d = 0; d < DIM; ++d) { double v = (double)row[d]; s += v * v; }
  c2f[j] = (float)s;
  c2d[j] = s;
}

// ---- kernel 2: score GEMM + per-row running min + margin capture ----
// block: 256 threads, owns 64 rows x ALL 8192 codes (rows exclusive -> no
// global atomics). tx = tid&31 -> 8 codes (tx*4+g*128+jj), ty = tid>>5 -> 8 rows.
__global__ __launch_bounds__(256) void k_gemm(
    const float* __restrict__ z, const float* __restrict__ cb,
    const float* __restrict__ c2f, unsigned long long* __restrict__ rowpack,
    uint32_t* __restrict__ candCnt, uint32_t* __restrict__ candIdx) {
  __shared__ float A[DIM][GEMM_BM];        // 64 KB, A[d][m]
  __shared__ float B[GEMM_BK][GEMM_BN];    // 16 KB, B[k][j]
  __shared__ unsigned long long rp[GEMM_BM];
  __shared__ uint32_t cnt[GEMM_BM];
  __shared__ uint32_t cidx[GEMM_BM][CAP];

  const int tid = threadIdx.x;
  const int tx = tid & 31;
  const int ty = tid >> 5;
  const int row0 = blockIdx.x * GEMM_BM;

  if (tid < GEMM_BM) { rp[tid] = ~0ull; cnt[tid] = 0u; }

  // stage A transposed: A[d][m] = z[row0+m][d]
  for (int it = 0; it < 16; ++it) {
    int id = it * 256 + tid;   // float4 id, 4096 total
    int m = id >> 6;
    int dg = id & 63;
    const float4 v = *reinterpret_cast<const float4*>(
        z + (size_t)(row0 + m) * DIM + dg * 4);
    A[dg * 4 + 0][m] = v.x;
    A[dg * 4 + 1][m] = v.y;
    A[dg * 4 + 2][m] = v.z;
    A[dg * 4 + 3][m] = v.w;
  }
  __syncthreads();

  for (int j0 = 0; j0 < NCODES; j0 += GEMM_BN) {
    float acc[8][8];
#pragma unroll
    for (int i = 0; i < 8; ++i)
#pragma unroll
      for (int j = 0; j < 8; ++j) acc[i][j] = 0.f;

    for (int kc = 0; kc < DIM; kc += GEMM_BK) {
      // stage B chunk: thread t -> code j0+t, dims kc..kc+15 (one 64B line)
      {
        const float* src = cb + (size_t)(j0 + tid) * DIM + kc;
#pragma unroll
        for (int f = 0; f < 4; ++f) {
          float4 v = *reinterpret_cast<const float4*>(src + f * 4);
          B[f * 4 + 0][tid] = v.x;
          B[f * 4 + 1][tid] = v.y;
          B[f * 4 + 2][tid] = v.z;
          B[f * 4 + 3][tid] = v.w;
        }
      }
      __syncthreads();
#pragma unroll
      for (int k = 0; k < GEMM_BK; ++k) {
        float a[8], b[8];
        const float4 a0 = *reinterpret_cast<const float4*>(&A[kc + k][ty * 8]);
        const float4 a1 = *reinterpret_cast<const float4*>(&A[kc + k][ty * 8 + 4]);
        a[0] = a0.x; a[1] = a0.y; a[2] = a0.z; a[3] = a0.w;
        a[4] = a1.x; a[5] = a1.y; a[6] = a1.z; a[7] = a1.w;
        const float4 b0 = *reinterpret_cast<const float4*>(&B[k][tx * 4]);
        const float4 b1 = *reinterpret_cast<const float4*>(&B[k][128 + tx * 4]);
        b[0] = b0.x; b[1] = b0.y; b[2] = b0.z; b[3] = b0.w;
        b[4] = b1.x; b[5] = b1.y; b[6] = b1.z; b[7] = b1.w;
#pragma unroll
        for (int i = 0; i < 8; ++i)
#pragma unroll
          for (int j = 0; j < 8; ++j) acc[i][j] += a[i] * b[j];
      }
      __syncthreads();
    }

    // per-row packed (score,idx) min; lexicographic => tie -> lowest index
#pragma unroll
    for (int i = 0; i < 8; ++i) {
      const int r = ty * 8 + i;
      unsigned long long best = ~0ull;
#pragma unroll
      for (int g = 0; g < 2; ++g)
#pragma unroll
        for (int jj = 0; jj < 4; ++jj) {
          const int jl = g * 128 + tx * 4 + jj;
          const float sc = c2f[j0 + jl] - 2.0f * acc[i][g * 4 + jj];
          const unsigned long long p =
              ((unsigned long long)enc_f32(sc) << 32) | (unsigned)(j0 + jl);
          if (p < best) best = p;
        }
      atomicMin(&rp[r], best);
    }
    __syncthreads();
    // capture candidates within MARGIN of running min (conservative superset
    // of final near-min set since rp is monotone decreasing)
#pragma unroll
    for (int i = 0; i < 8; ++i) {
      const int r = ty * 8 + i;
      const float thr = dec_f32((uint32_t)(rp[r] >> 32)) + MARGIN;
#pragma unroll
      for (int g = 0; g < 2; ++g)
#pragma unroll
        for (int jj = 0; jj < 4; ++jj) {
          const int jl = g * 128 + tx * 4 + jj;
          const float sc = c2f[j0 + jl] - 2.0f * acc[i][g * 4 + jj];
          if (sc <= thr) {
            uint32_t p = atomicAdd(&cnt[r], 1u);
            if (p < CAP) cidx[r][p] = (uint32_t)(j0 + jl);
          }
        }
    }
    __syncthreads();
  }

  if (tid < GEMM_BM) {
    rowpack[row0 + tid] = rp[tid];
    uint32_t c = cnt[tid]; if (c > CAP) c = CAP;
    candCnt[row0 + tid] = c;
    for (uint32_t q = 0; q < c; ++q)
      candIdx[(size_t)(row0 + tid) * CAP + q] = cidx[tid][q];
  }
}

// ---- kernel 3: fp64 re-score of captured candidates, exact argmin ----
__global__ __launch_bounds__(256) void k_refine(
    const float* __restrict__ z, const float* __restrict__ cb,
    const double* __restrict__ c2d, const unsigned long long* __restrict__ rowpack,
    const uint32_t* __restrict__ candCnt, const uint32_t* __restrict__ candIdx,
    uint32_t* __restrict__ fidx) {
  const int w = threadIdx.x >> 6;
  const int lane = threadIdx.x & 63;
  const int r = blockIdx.x * 4 + w;
  float zv[4];
#pragma unroll
  for (int q = 0; q < 4; ++q) zv[q] = z[(size_t)r * DIM + lane * 4 + q];
  double bestS = 1e300; uint32_t bestJ = 0xFFFFFFFFu;
  const uint32_t rpj = (uint32_t)(rowpack[r] & 0xFFFFFFFFull);
  const uint32_t cn = candCnt[r];
  for (uint32_t c = 0; c <= cn; ++c) {
    const uint32_t j = (c == 0) ? rpj : candIdx[(size_t)r * CAP + (c - 1)];
    double acc = 0.0;
#pragma unroll
    for (int q = 0; q < 4; ++q)
      acc += (double)zv[q] * (double)cb[(size_t)j * DIM + lane * 4 + q];
#pragma unroll
    for (int off = 32; off > 0; off >>= 1) acc += __shfl_xor(acc, off);
    const double s = c2d[j] - 2.0 * acc;
    if (s < bestS || (s == bestS && j < bestJ)) { bestS = s; bestJ = j; }
  }
  if (lane == 0) fidx[r] = bestJ;
}

// ---- kernel 4: gather z_q, write output, accumulate MSE in fp64 ----
__global__ __launch_bounds__(256) void k_out(
    const float* __restrict__ z, const float* __restrict__ cb,
    const uint32_t* __restrict__ fidx, float* __restrict__ out,
    double* __restrict__ lossAcc) {
  const int r = blockIdx.x;
  const int d = threadIdx.x;
  const uint32_t j = fidx[r];
  const float q = cb[(size_t)j * DIM + d];
  const float zv = z[(size_t)r * DIM + d];
  out[(size_t)r * DIM + d] = q;
  const float df = zv - q;
  double v = (double)df * (double)df;
#pragma unroll
  for (int off = 32; off > 0; off >>= 1) v += __shfl_xor(v, off);
  __shared__ double part[4];
  if ((threadIdx.x & 63) == 0) part[threadIdx.x >> 6] = v;
  __syncthreads();
  if (threadIdx.x == 0) {
    atomicAdd(lossAcc, part[0] + part[1] + part[2] + part[3]);
  }
}

// ---- kernel 5: finalize loss ----
__global__ void k_fin(const double* __restrict__ lossAcc, float* __restrict__ out) {
  if (threadIdx.x == 0 && blockIdx.x == 0) {
    const double mse = lossAcc[0] / (double)((size_t)NROWS * DIM);
    out[(size_t)NROWS * DIM] = (float)(0.1 * mse + mse);
  }
}

extern "C" void kernel_launch(void* const* d_in, const int* in_sizes, int n_in,
                              void* d_out, int out_size, void* d_ws, size_t ws_size,
                              hipStream_t stream) {
  const float* z  = (const float*)d_in[0];
  const float* cb = (const float*)d_in[1];
  float* out = (float*)d_out;
  char* ws = (char*)d_ws;
  float*  c2f = (float*)(ws + OFF_C2F);
  double* c2d = (double*)(ws + OFF_C2D);
  unsigned long long* rowpack = (unsigned long long*)(ws + OFF_ROWPACK);
  uint32_t* candCnt = (uint32_t*)(ws + OFF_CNT);
  uint32_t* candIdx = (uint32_t*)(ws + OFF_CIDX);
  uint32_t* fidx    = (uint32_t*)(ws + OFF_FIDX);
  double* lossAcc   = (double*)(ws + OFF_LOSS);

  hipMemsetAsync(lossAcc, 0, sizeof(double), stream);
  hipLaunchKernelGGL(k_c2, dim3(NCODES / 256), dim3(256), 0, stream, cb, c2f, c2d);
  hipLaunchKernelGGL(k_gemm, dim3(NROWS / GEMM_BM), dim3(256), 0, stream,
                     z, cb, c2f, rowpack, candCnt, candIdx);
  hipLaunchKernelGGL(k_refine, dim3(NROWS / 4), dim3(256), 0, stream,
                     z, cb, c2d, rowpack, candCnt, candIdx, fidx);
  hipLaunchKernelGGL(k_out, dim3(NROWS), dim3(256), 0, stream,
                     z, cb, fidx, out, lossAcc);
  hipLaunchKernelGGL(k_fin, dim3(1), dim3(64), 0, stream, lossAcc, out);
}

// Round 2
// 595.948 us; speedup vs baseline: 2.6191x; 2.6191x over previous
//
#include <hip/hip_runtime.h>
#include <hip/hip_bf16.h>
#include <stdint.h>

#define NROWS 16384
#define NCODES 8192
#define DIM 256
#define CAP 16
#define MARGIN 1e-3f

// workspace layout (bytes)
#define OFF_C2F     0u         // float[8192]              32768
#define OFF_C2D     32768u     // double[8192]             65536
#define OFF_ROWPACK 98304u     // u64[16384]              131072
#define OFF_CNT     229376u    // u32[16384]               65536
#define OFF_CIDX    294912u    // u32[16384][CAP]        1048576
#define OFF_FIDX    1343488u   // u32[16384]               65536
#define OFF_LOSS    1409024u   // double[1]                  128 (pad)
#define OFF_Z16     1409152u   // u16[16384*256]         8388608
#define OFF_CB16    9797760u   // u16[8192*256]          4194304
// total ~13.99 MB

typedef __attribute__((ext_vector_type(8))) short bf16x8;
typedef __attribute__((ext_vector_type(4))) float f32x4;

__device__ __forceinline__ uint32_t enc_f32(float f) {
  uint32_t u = __float_as_uint(f);
  return (u & 0x80000000u) ? ~u : (u | 0x80000000u);
}
__device__ __forceinline__ float dec_f32(uint32_t e) {
  uint32_t b = (e & 0x80000000u) ? (e & 0x7fffffffu) : ~e;
  return __uint_as_float(b);
}
__device__ __forceinline__ unsigned short f2bf(float f) {
  uint32_t u = __float_as_uint(f);
  u += 0x7fffu + ((u >> 16) & 1u);   // RNE (inputs finite)
  return (unsigned short)(u >> 16);
}
__device__ __forceinline__ void gload16(const void* g, void* l) {
  __builtin_amdgcn_global_load_lds(
      (const __attribute__((address_space(1))) unsigned int*)g,
      (__attribute__((address_space(3))) unsigned int*)l, 16, 0, 0);
}
__device__ __forceinline__ unsigned long long umin64(unsigned long long a,
                                                     unsigned long long b) {
  return a < b ? a : b;
}

// ---- kernel 0: fp32 -> bf16 conversion (vectorized) ----
__global__ __launch_bounds__(256) void k_cvt(const float* __restrict__ src,
                                             unsigned short* __restrict__ dst,
                                             int n4) {
  int i = blockIdx.x * 256 + threadIdx.x;
  if (i >= n4) return;
  float4 v = reinterpret_cast<const float4*>(src)[i];
  ushort4 o;
  o.x = f2bf(v.x); o.y = f2bf(v.y); o.z = f2bf(v.z); o.w = f2bf(v.w);
  reinterpret_cast<ushort4*>(dst)[i] = o;
}

// ---- kernel 1: per-code squared norms, wave per code ----
__global__ __launch_bounds__(256) void k_c2(const float* __restrict__ cb,
                                            float* __restrict__ c2f,
                                            double* __restrict__ c2d) {
  const int w = threadIdx.x >> 6, lane = threadIdx.x & 63;
  const int j = blockIdx.x * 4 + w;
  float4 v = *reinterpret_cast<const float4*>(cb + (size_t)j * DIM + lane * 4);
  double s = (double)v.x * v.x + (double)v.y * v.y +
             (double)v.z * v.z + (double)v.w * v.w;
#pragma unroll
  for (int off = 32; off > 0; off >>= 1) s += __shfl_xor(s, off);
  if (lane == 0) { c2f[j] = (float)s; c2d[j] = s; }
}

// ---- kernel 2: bf16 MFMA score GEMM (128x128 tile, BK=64) + fused
//      per-row packed-min + margin capture ----
__global__ __launch_bounds__(256) void k_score(
    const unsigned short* __restrict__ z16, const unsigned short* __restrict__ cb16,
    const float* __restrict__ c2f, unsigned long long* __restrict__ rowpack,
    uint32_t* __restrict__ candCnt, uint32_t* __restrict__ candIdx) {
  __shared__ unsigned short Asm[128 * 64];   // [row][k] bf16, 16 KB
  __shared__ unsigned short Bsm[128 * 64];   // [code][k] bf16, 16 KB
  __shared__ unsigned long long rp_blk[128];
  __shared__ unsigned long long obs[128];

  const int tid = threadIdx.x;
  const int lane = tid & 63;
  const int w = tid >> 6;
  const int wr = w >> 1, wc = w & 1;       // wave tile: 64x64
  const int l15 = lane & 15, l4 = lane >> 4;

  const int bx = blockIdx.x;
  const int row0 = (bx >> 6) * 128;        // 128 row tiles
  const int col0 = (bx & 63) * 128;        // 64 col tiles

  if (tid < 128) rp_blk[tid] = ~0ull;

  f32x4 acc[4][4];
#pragma unroll
  for (int mi = 0; mi < 4; ++mi)
#pragma unroll
    for (int ni = 0; ni < 4; ++ni) acc[mi][ni] = (f32x4){0.f, 0.f, 0.f, 0.f};

  const int srow = tid >> 3;               // 0..31
  const int scol = (tid & 7) * 8;          // bf16 elems within 64-chunk
  const unsigned wbase = (unsigned)(tid >> 6) * 1024u;  // wave-uniform LDS base

  for (int kc = 0; kc < DIM; kc += 64) {
    // stage A,B tiles: 4 issues each of 256 threads x 16 B
#pragma unroll
    for (int i = 0; i < 4; ++i) {
      const unsigned short* ga =
          z16 + (size_t)(row0 + i * 32 + srow) * DIM + kc + scol;
      gload16(ga, (char*)Asm + i * 4096 + wbase);
      const unsigned short* gb =
          cb16 + (size_t)(col0 + i * 32 + srow) * DIM + kc + scol;
      gload16(gb, (char*)Bsm + i * 4096 + wbase);
    }
    __syncthreads();
#pragma unroll
    for (int kk = 0; kk < 2; ++kk) {
      bf16x8 a[4], b[4];
#pragma unroll
      for (int mi = 0; mi < 4; ++mi) {
        const int r = wr * 64 + mi * 16 + l15;
        a[mi] = *reinterpret_cast<const bf16x8*>(
            (const char*)Asm + r * 128 + kk * 64 + l4 * 16);
      }
#pragma unroll
      for (int ni = 0; ni < 4; ++ni) {
        const int r = wc * 64 + ni * 16 + l15;
        b[ni] = *reinterpret_cast<const bf16x8*>(
            (const char*)Bsm + r * 128 + kk * 64 + l4 * 16);
      }
#pragma unroll
      for (int mi = 0; mi < 4; ++mi)
#pragma unroll
        for (int ni = 0; ni < 4; ++ni)
          acc[mi][ni] = __builtin_amdgcn_mfma_f32_16x16x32_bf16(
              a[mi], b[ni], acc[mi][ni], 0, 0, 0);
    }
    __syncthreads();
  }

  // ---- epilogue: score = c2f[col] - 2*dot; packed (score,col) min ----
  float c2v[4];
#pragma unroll
  for (int ni = 0; ni < 4; ++ni)
    c2v[ni] = c2f[col0 + wc * 64 + ni * 16 + l15];

#pragma unroll
  for (int mi = 0; mi < 4; ++mi) {
#pragma unroll
    for (int q = 0; q < 4; ++q) {
      unsigned long long pm = ~0ull;
#pragma unroll
      for (int ni = 0; ni < 4; ++ni) {
        const float sc = c2v[ni] - 2.0f * acc[mi][ni][q];
        const int col = col0 + wc * 64 + ni * 16 + l15;
        const unsigned long long p =
            ((unsigned long long)enc_f32(sc) << 32) | (unsigned)col;
        pm = umin64(pm, p);
      }
#pragma unroll
      for (int off = 1; off < 16; off <<= 1)
        pm = umin64(pm, (unsigned long long)__shfl_xor(pm, off));
      if (l15 == 0) {
        const int rloc = wr * 64 + mi * 16 + l4 * 4 + q;
        atomicMin(&rp_blk[rloc], pm);
      }
    }
  }
  __syncthreads();

  // push block min to global, observe post-push global min (device-scope atomic)
  if (tid < 128) {
    const unsigned long long mine = rp_blk[tid];
    const unsigned long long old = atomicMin(&rowpack[row0 + tid], mine);
    obs[tid] = umin64(old, mine);
  }
  __syncthreads();

  // capture: everything within MARGIN of the observed global min
#pragma unroll
  for (int mi = 0; mi < 4; ++mi) {
#pragma unroll
    for (int q = 0; q < 4; ++q) {
      const int rloc = wr * 64 + mi * 16 + l4 * 4 + q;
      const float thr = dec_f32((uint32_t)(obs[rloc] >> 32)) + MARGIN;
#pragma unroll
      for (int ni = 0; ni < 4; ++ni) {
        const float sc = c2v[ni] - 2.0f * acc[mi][ni][q];
        if (sc <= thr) {
          const int col = col0 + wc * 64 + ni * 16 + l15;
          const int grow = row0 + rloc;
          const uint32_t p = atomicAdd(&candCnt[grow], 1u);
          if (p < CAP) candIdx[(size_t)grow * CAP + p] = (uint32_t)col;
        }
      }
    }
  }
}

// ---- kernel 3: fp64 re-score of captured candidates, exact argmin ----
__global__ __launch_bounds__(256) void k_refine(
    const float* __restrict__ z, const float* __restrict__ cb,
    const double* __restrict__ c2d, const unsigned long long* __restrict__ rowpack,
    const uint32_t* __restrict__ candCnt, const uint32_t* __restrict__ candIdx,
    uint32_t* __restrict__ fidx) {
  const int w = threadIdx.x >> 6;
  const int lane = threadIdx.x & 63;
  const int r = blockIdx.x * 4 + w;
  float zv[4];
#pragma unroll
  for (int q = 0; q < 4; ++q) zv[q] = z[(size_t)r * DIM + lane * 4 + q];
  double bestS = 1e300; uint32_t bestJ = 0xFFFFFFFFu;
  const uint32_t rpj = (uint32_t)(rowpack[r] & 0xFFFFFFFFull);
  uint32_t cn = candCnt[r];
  if (cn > CAP) cn = CAP;
  for (uint32_t c = 0; c <= cn; ++c) {
    const uint32_t j = (c == 0) ? rpj : candIdx[(size_t)r * CAP + (c - 1)];
    double acc = 0.0;
#pragma unroll
    for (int q = 0; q < 4; ++q)
      acc += (double)zv[q] * (double)cb[(size_t)j * DIM + lane * 4 + q];
#pragma unroll
    for (int off = 32; off > 0; off >>= 1) acc += __shfl_xor(acc, off);
    const double s = c2d[j] - 2.0 * acc;
    if (s < bestS || (s == bestS && j < bestJ)) { bestS = s; bestJ = j; }
  }
  if (lane == 0) fidx[r] = bestJ;
}

// ---- kernel 4: gather z_q, write output, accumulate MSE in fp64 ----
__global__ __launch_bounds__(256) void k_out(
    const float* __restrict__ z, const float* __restrict__ cb,
    const uint32_t* __restrict__ fidx, float* __restrict__ out,
    double* __restrict__ lossAcc) {
  const int r = blockIdx.x;
  const int d = threadIdx.x;
  const uint32_t j = fidx[r];
  const float q = cb[(size_t)j * DIM + d];
  const float zv = z[(size_t)r * DIM + d];
  out[(size_t)r * DIM + d] = q;
  const float df = zv - q;
  double v = (double)df * (double)df;
#pragma unroll
  for (int off = 32; off > 0; off >>= 1) v += __shfl_xor(v, off);
  __shared__ double part[4];
  if ((threadIdx.x & 63) == 0) part[threadIdx.x >> 6] = v;
  __syncthreads();
  if (threadIdx.x == 0) {
    atomicAdd(lossAcc, part[0] + part[1] + part[2] + part[3]);
  }
}

// ---- kernel 5: finalize loss ----
__global__ void k_fin(const double* __restrict__ lossAcc, float* __restrict__ out) {
  if (threadIdx.x == 0 && blockIdx.x == 0) {
    const double mse = lossAcc[0] / (double)((size_t)NROWS * DIM);
    out[(size_t)NROWS * DIM] = (float)(0.1 * mse + mse);
  }
}

extern "C" void kernel_launch(void* const* d_in, const int* in_sizes, int n_in,
                              void* d_out, int out_size, void* d_ws, size_t ws_size,
                              hipStream_t stream) {
  const float* z  = (const float*)d_in[0];
  const float* cb = (const float*)d_in[1];
  float* out = (float*)d_out;
  char* ws = (char*)d_ws;
  float*  c2f = (float*)(ws + OFF_C2F);
  double* c2d = (double*)(ws + OFF_C2D);
  unsigned long long* rowpack = (unsigned long long*)(ws + OFF_ROWPACK);
  uint32_t* candCnt = (uint32_t*)(ws + OFF_CNT);
  uint32_t* candIdx = (uint32_t*)(ws + OFF_CIDX);
  uint32_t* fidx    = (uint32_t*)(ws + OFF_FIDX);
  double* lossAcc   = (double*)(ws + OFF_LOSS);
  unsigned short* z16  = (unsigned short*)(ws + OFF_Z16);
  unsigned short* cb16 = (unsigned short*)(ws + OFF_CB16);

  hipMemsetAsync(rowpack, 0xFF, NROWS * sizeof(unsigned long long), stream);
  hipMemsetAsync(candCnt, 0, NROWS * sizeof(uint32_t), stream);
  hipMemsetAsync(lossAcc, 0, sizeof(double), stream);

  hipLaunchKernelGGL(k_cvt, dim3(NROWS * DIM / 4 / 256), dim3(256), 0, stream,
                     z, z16, NROWS * DIM / 4);
  hipLaunchKernelGGL(k_cvt, dim3(NCODES * DIM / 4 / 256), dim3(256), 0, stream,
                     cb, cb16, NCODES * DIM / 4);
  hipLaunchKernelGGL(k_c2, dim3(NCODES / 4), dim3(256), 0, stream, cb, c2f, c2d);
  hipLaunchKernelGGL(k_score, dim3((NROWS / 128) * (NCODES / 128)), dim3(256),
                     0, stream, z16, cb16, c2f, rowpack, candCnt, candIdx);
  hipLaunchKernelGGL(k_refine, dim3(NROWS / 4), dim3(256), 0, stream,
                     z, cb, c2d, rowpack, candCnt, candIdx, fidx);
  hipLaunchKernelGGL(k_out, dim3(NROWS), dim3(256), 0, stream,
                     z, cb, fidx, out, lossAcc);
  hipLaunchKernelGGL(k_fin, dim3(1), dim3(64), 0, stream, lossAcc, out);
}

// Round 3
// 210.211 us; speedup vs baseline: 7.4250x; 2.8350x over previous
//
#include <hip/hip_runtime.h>
#include <hip/hip_bf16.h>
#include <stdint.h>

#define NROWS 16384
#define NCODES 8192
#define DIM 256
#define CAP 16
#define MARGIN 1e-4f

#define BROWS 64
#define PCOLS 4096
#define BCOLS 128
#define NCITER (PCOLS / BCOLS)   // 32

// workspace layout (bytes)
#define OFF_C2F     0u          // float[8192]            32768
#define OFF_C2D     32768u      // double[8192]           65536
#define OFF_ROWPACK 98304u      // u64[16384]            131072
#define OFF_CNT     229376u     // u32[16384]             65536
#define OFF_CIDX    294912u     // u32[16384][CAP]      1048576
#define OFF_FIDX    1343488u    // u32[16384]             65536
#define OFF_LSLOT   1409024u    // double[256]             2048
#define OFF_Z16     1411072u    // u16[16384*256]       8388608
#define OFF_CB16    9799680u    // u16[8192*256]        4194304

typedef __attribute__((ext_vector_type(8))) short bf16x8;
typedef __attribute__((ext_vector_type(4))) float f32x4;

__device__ __forceinline__ uint32_t enc_f32(float f) {
  uint32_t u = __float_as_uint(f);
  return (u & 0x80000000u) ? ~u : (u | 0x80000000u);
}
__device__ __forceinline__ float dec_f32(uint32_t e) {
  uint32_t b = (e & 0x80000000u) ? (e & 0x7fffffffu) : ~e;
  return __uint_as_float(b);
}
__device__ __forceinline__ unsigned short f2bf(float f) {
  uint32_t u = __float_as_uint(f);
  u += 0x7fffu + ((u >> 16) & 1u);   // RNE (inputs finite)
  return (unsigned short)(u >> 16);
}
__device__ __forceinline__ void gload16(const void* g, void* l) {
  __builtin_amdgcn_global_load_lds(
      (const __attribute__((address_space(1))) unsigned int*)g,
      (__attribute__((address_space(3))) unsigned int*)l, 16, 0, 0);
}
__device__ __forceinline__ unsigned long long umin64(unsigned long long a,
                                                     unsigned long long b) {
  return a < b ? a : b;
}

// ---- kernel 1: fused prep — z cvt (blocks 0..4095), cb cvt + norms (4096..6143)
__global__ __launch_bounds__(256) void k_prep(const float* __restrict__ z,
                                              const float* __restrict__ cb,
                                              unsigned short* __restrict__ z16,
                                              unsigned short* __restrict__ cb16,
                                              float* __restrict__ c2f,
                                              double* __restrict__ c2d) {
  const int bid = blockIdx.x;
  if (bid < 4096) {
    const int i = bid * 256 + threadIdx.x;
    float4 v = reinterpret_cast<const float4*>(z)[i];
    ushort4 o = {f2bf(v.x), f2bf(v.y), f2bf(v.z), f2bf(v.w)};
    reinterpret_cast<ushort4*>(z16)[i] = o;
  } else {
    const int w = threadIdx.x >> 6, lane = threadIdx.x & 63;
    const int j = (bid - 4096) * 4 + w;
    float4 v = *reinterpret_cast<const float4*>(cb + (size_t)j * DIM + lane * 4);
    ushort4 o = {f2bf(v.x), f2bf(v.y), f2bf(v.z), f2bf(v.w)};
    *reinterpret_cast<ushort4*>(cb16 + (size_t)j * DIM + lane * 4) = o;
    double s = (double)v.x * v.x + (double)v.y * v.y +
               (double)v.z * v.z + (double)v.w * v.w;
#pragma unroll
    for (int off = 32; off > 0; off >>= 1) s += __shfl_xor(s, off);
    if (lane == 0) { c2f[j] = (float)s; c2d[j] = s; }
  }
}

// ---- kernel 2: panel-persistent MFMA score + register best-2 argmin ----
// block: 256 thr / 4 waves. Panel: 64 rows x 4096 cols. Per col-iter: 64x128
// tile, waves in 2x2 (wr row-half 32 rows, wc col-half 64 cols).
// A held in registers for whole kernel; B double-buffered, 1 barrier/chunk.
__global__ __launch_bounds__(256, 2) void k_score(
    const unsigned short* __restrict__ z16, const unsigned short* __restrict__ cb16,
    const float* __restrict__ c2f, unsigned long long* __restrict__ rowpack,
    uint32_t* __restrict__ candCnt, uint32_t* __restrict__ candIdx) {
  __shared__ unsigned short Asm[BROWS * DIM];    // 32 KB linear [row][k]
  __shared__ unsigned short Bsm[2][BCOLS * 64];  // 2 x 16 KB, XOR-swizzled rows
  __shared__ unsigned long long rp_sh[BROWS];
  __shared__ unsigned long long obs_sh[BROWS];

  const int tid = threadIdx.x;
  const int lane = tid & 63;
  const int w = tid >> 6;
  const int wr = w >> 1, wc = w & 1;
  const int l15 = lane & 15, l4 = lane >> 4;

  const int bx = blockIdx.x;
  const int row0 = (bx >> 1) * BROWS;
  const int col0 = (bx & 1) * PCOLS;

  if (tid < BROWS) rp_sh[tid] = ~0ull;

  const unsigned wbase = (unsigned)w * 1024u;

  // ---- stage A once (linear) ----
  {
    const int r = tid >> 5;
    const int e0 = (tid & 31) * 8;
#pragma unroll
    for (int i = 0; i < 8; ++i)
      gload16(z16 + (size_t)(row0 + i * 8 + r) * DIM + e0,
              (char*)Asm + i * 4096 + wbase);
  }
  // B staging source constants: swizzle folds to per-thread constant.
  // LDS slot (code c, byte kb) holds global k-byte (kb ^ ((c&7)<<4)).
  const int bc_loc = tid >> 3;                                        // 0..31
  const int kswz_e = ((((tid & 7) * 16) ^ (((tid >> 3) & 7) << 4)) >> 1);

  __syncthreads();   // A staged (vmcnt drained at barrier)

  // ---- A fragments to registers (whole K), held for entire kernel ----
  bf16x8 a_reg[2][8];
#pragma unroll
  for (int mi = 0; mi < 2; ++mi)
#pragma unroll
    for (int kt = 0; kt < 8; ++kt) {
      const int r = wr * 32 + mi * 16 + l15;
      a_reg[mi][kt] = *reinterpret_cast<const bf16x8*>(
          (const char*)Asm + r * 512 + kt * 64 + l4 * 16);
    }

#define STAGE_B(citer_, kc_, buf_) do {                                        \
    const int cstart_ = col0 + (citer_) * BCOLS;                               \
    _Pragma("unroll")                                                          \
    for (int i_ = 0; i_ < 4; ++i_)                                             \
      gload16(cb16 + (size_t)(cstart_ + i_ * 32 + bc_loc) * DIM +              \
                  (kc_) * 64 + kswz_e,                                         \
              (char*)Bsm[buf_] + i_ * 4096 + wbase);                           \
  } while (0)

#define COMPUTE(kc_, buf_) do {                                                \
    _Pragma("unroll")                                                          \
    for (int kk_ = 0; kk_ < 2; ++kk_) {                                        \
      bf16x8 bf_[4];                                                           \
      _Pragma("unroll")                                                        \
      for (int ni_ = 0; ni_ < 4; ++ni_) {                                      \
        const int c_ = wc * 64 + ni_ * 16 + l15;                               \
        const int kb_ = (kk_ * 64 + l4 * 16) ^ ((l15 & 7) << 4);               \
        bf_[ni_] = *reinterpret_cast<const bf16x8*>(                           \
            (const char*)Bsm[buf_] + c_ * 128 + kb_);                          \
      }                                                                        \
      _Pragma("unroll")                                                        \
      for (int mi_ = 0; mi_ < 2; ++mi_)                                        \
        _Pragma("unroll")                                                      \
        for (int ni_ = 0; ni_ < 4; ++ni_)                                      \
          acc[mi_][ni_] = __builtin_amdgcn_mfma_f32_16x16x32_bf16(             \
              a_reg[mi_][(kc_) * 2 + kk_], bf_[ni_], acc[mi_][ni_], 0, 0, 0);  \
    }                                                                          \
  } while (0)

  f32x4 acc[2][4];
  float b0v[8], b1v[8];
  uint32_t b0c[8], b1c[8];
#pragma unroll
  for (int s = 0; s < 8; ++s) {
    b0v[s] = 1e30f; b1v[s] = 1e30f; b0c[s] = 0u; b1c[s] = 0u;
  }

  STAGE_B(0, 0, 0);

  for (int citer = 0; citer < NCITER; ++citer) {
#pragma unroll
    for (int mi = 0; mi < 2; ++mi)
#pragma unroll
      for (int ni = 0; ni < 4; ++ni) acc[mi][ni] = (f32x4){0.f, 0.f, 0.f, 0.f};

    __syncthreads();                 // drains STAGE_B(citer,0)
    STAGE_B(citer, 1, 1);
    COMPUTE(0, 0);
    __syncthreads();
    STAGE_B(citer, 2, 0);
    COMPUTE(1, 1);
    __syncthreads();
    STAGE_B(citer, 3, 1);
    COMPUTE(2, 0);
    __syncthreads();
    if (citer + 1 < NCITER) STAGE_B(citer + 1, 0, 0);
    COMPUTE(3, 1);

    // ---- per-col-iter epilogue: register best-2 per (lane,row-slot) ----
    const int cstart = col0 + citer * BCOLS + wc * 64;
    const uint32_t cbase = (uint32_t)(cstart + l15);
    float c2v[4];
#pragma unroll
    for (int ni = 0; ni < 4; ++ni) c2v[ni] = c2f[cstart + ni * 16 + l15];
#pragma unroll
    for (int mi = 0; mi < 2; ++mi)
#pragma unroll
      for (int q = 0; q < 4; ++q) {
        const int s = mi * 4 + q;
        const float s0 = fmaf(-2.f, acc[mi][0][q], c2v[0]);
        const float s1 = fmaf(-2.f, acc[mi][1][q], c2v[1]);
        const float s2 = fmaf(-2.f, acc[mi][2][q], c2v[2]);
        const float s3 = fmaf(-2.f, acc[mi][3][q], c2v[3]);
        const float m01 = fminf(s0, s1);
        const uint32_t c01 = s1 < s0 ? cbase + 16u : cbase;
        const float m23 = fminf(s2, s3);
        const uint32_t c23 = s3 < s2 ? cbase + 48u : cbase + 32u;
        const float mv = fminf(m01, m23);
        const uint32_t mc = m23 < m01 ? c23 : c01;
        const bool lt0 = mv < b0v[s];
        const bool lt1 = mv < b1v[s];
        b1v[s] = lt0 ? b0v[s] : (lt1 ? mv : b1v[s]);
        b1c[s] = lt0 ? b0c[s] : (lt1 ? mc : b1c[s]);
        b0v[s] = lt0 ? mv : b0v[s];
        b0c[s] = lt0 ? mc : b0c[s];
      }
  }

  // ---- block end: cross-lane reduce, global merge, margin capture ----
#pragma unroll
  for (int mi = 0; mi < 2; ++mi)
#pragma unroll
    for (int q = 0; q < 4; ++q) {
      const int s = mi * 4 + q;
      const int rloc = wr * 32 + mi * 16 + l4 * 4 + q;
      unsigned long long p =
          ((unsigned long long)enc_f32(b0v[s]) << 32) | b0c[s];
#pragma unroll
      for (int off = 1; off < 16; off <<= 1)
        p = umin64(p, (unsigned long long)__shfl_xor(p, off));
      if (l15 == 0) atomicMin(&rp_sh[rloc], p);
    }
  __syncthreads();
  if (tid < BROWS) {
    const unsigned long long mine = rp_sh[tid];
    const unsigned long long old = atomicMin(&rowpack[row0 + tid], mine);
    obs_sh[tid] = umin64(old, mine);
  }
  __syncthreads();
#pragma unroll
  for (int mi = 0; mi < 2; ++mi)
#pragma unroll
    for (int q = 0; q < 4; ++q) {
      const int s = mi * 4 + q;
      const int rloc = wr * 32 + mi * 16 + l4 * 4 + q;
      const float thr = dec_f32((uint32_t)(obs_sh[rloc] >> 32)) + MARGIN;
      const int grow = row0 + rloc;
      if (b0v[s] <= thr) {
        const uint32_t pidx = atomicAdd(&candCnt[grow], 1u);
        if (pidx < CAP) candIdx[(size_t)grow * CAP + pidx] = b0c[s];
      }
      if (b1v[s] <= thr) {
        const uint32_t pidx = atomicAdd(&candCnt[grow], 1u);
        if (pidx < CAP) candIdx[(size_t)grow * CAP + pidx] = b1c[s];
      }
    }
#undef STAGE_B
#undef COMPUTE
}

// ---- kernel 3: fp64 re-score of candidates, exact argmin ----
__global__ __launch_bounds__(256) void k_refine(
    const float* __restrict__ z, const float* __restrict__ cb,
    const double* __restrict__ c2d, const unsigned long long* __restrict__ rowpack,
    const uint32_t* __restrict__ candCnt, const uint32_t* __restrict__ candIdx,
    uint32_t* __restrict__ fidx) {
  const int w = threadIdx.x >> 6;
  const int lane = threadIdx.x & 63;
  const int r = blockIdx.x * 4 + w;
  float zv[4];
#pragma unroll
  for (int q = 0; q < 4; ++q) zv[q] = z[(size_t)r * DIM + lane * 4 + q];
  double bestS = 1e300; uint32_t bestJ = 0xFFFFFFFFu;
  const uint32_t rpj = (uint32_t)(rowpack[r] & 0xFFFFFFFFull);
  uint32_t cn = candCnt[r];
  if (cn > CAP) cn = CAP;
  for (uint32_t c = 0; c <= cn; ++c) {
    const uint32_t j = (c == 0) ? rpj : candIdx[(size_t)r * CAP + (c - 1)];
    double acc = 0.0;
#pragma unroll
    for (int q = 0; q < 4; ++q)
      acc += (double)zv[q] * (double)cb[(size_t)j * DIM + lane * 4 + q];
#pragma unroll
    for (int off = 32; off > 0; off >>= 1) acc += __shfl_xor(acc, off);
    const double s = c2d[j] - 2.0 * acc;
    if (s < bestS || (s == bestS && j < bestJ)) { bestS = s; bestJ = j; }
  }
  if (lane == 0) fidx[r] = bestJ;
}

// ---- kernel 4: gather z_q, write output, fp64 MSE into 256 slots ----
__global__ __launch_bounds__(256) void k_out(
    const float* __restrict__ z, const float* __restrict__ cb,
    const uint32_t* __restrict__ fidx, float* __restrict__ out,
    double* __restrict__ lossSlots) {
  const int r = blockIdx.x;
  const int d = threadIdx.x;
  const uint32_t j = fidx[r];
  const float q = cb[(size_t)j * DIM + d];
  const float zv = z[(size_t)r * DIM + d];
  out[(size_t)r * DIM + d] = q;
  const float df = zv - q;
  double v = (double)df * (double)df;
#pragma unroll
  for (int off = 32; off > 0; off >>= 1) v += __shfl_xor(v, off);
  __shared__ double part[4];
  if ((threadIdx.x & 63) == 0) part[threadIdx.x >> 6] = v;
  __syncthreads();
  if (threadIdx.x == 0)
    atomicAdd(&lossSlots[blockIdx.x & 255],
              part[0] + part[1] + part[2] + part[3]);
}

// ---- kernel 5: finalize loss ----
__global__ __launch_bounds__(256) void k_fin(const double* __restrict__ slots,
                                             float* __restrict__ out) {
  const int w = threadIdx.x >> 6, lane = threadIdx.x & 63;
  double v = slots[threadIdx.x];
#pragma unroll
  for (int off = 32; off > 0; off >>= 1) v += __shfl_xor(v, off);
  __shared__ double part[4];
  if (lane == 0) part[w] = v;
  __syncthreads();
  if (threadIdx.x == 0) {
    const double mse =
        (part[0] + part[1] + part[2] + part[3]) / (double)((size_t)NROWS * DIM);
    out[(size_t)NROWS * DIM] = (float)(1.1 * mse);   // 0.1*mse + mse
  }
}

extern "C" void kernel_launch(void* const* d_in, const int* in_sizes, int n_in,
                              void* d_out, int out_size, void* d_ws, size_t ws_size,
                              hipStream_t stream) {
  const float* z  = (const float*)d_in[0];
  const float* cb = (const float*)d_in[1];
  float* out = (float*)d_out;
  char* ws = (char*)d_ws;
  float*  c2f = (float*)(ws + OFF_C2F);
  double* c2d = (double*)(ws + OFF_C2D);
  unsigned long long* rowpack = (unsigned long long*)(ws + OFF_ROWPACK);
  uint32_t* candCnt = (uint32_t*)(ws + OFF_CNT);
  uint32_t* candIdx = (uint32_t*)(ws + OFF_CIDX);
  uint32_t* fidx    = (uint32_t*)(ws + OFF_FIDX);
  double* lossSlots = (double*)(ws + OFF_LSLOT);
  unsigned short* z16  = (unsigned short*)(ws + OFF_Z16);
  unsigned short* cb16 = (unsigned short*)(ws + OFF_CB16);

  hipMemsetAsync(rowpack, 0xFF, NROWS * sizeof(unsigned long long), stream);
  hipMemsetAsync(candCnt, 0, NROWS * sizeof(uint32_t), stream);
  hipMemsetAsync(lossSlots, 0, 256 * sizeof(double), stream);

  hipLaunchKernelGGL(k_prep, dim3(4096 + 2048), dim3(256), 0, stream,
                     z, cb, z16, cb16, c2f, c2d);
  hipLaunchKernelGGL(k_score, dim3((NROWS / BROWS) * (NCODES / PCOLS)),
                     dim3(256), 0, stream, z16, cb16, c2f, rowpack, candCnt,
                     candIdx);
  hipLaunchKernelGGL(k_refine, dim3(NROWS / 4), dim3(256), 0, stream,
                     z, cb, c2d, rowpack, candCnt, candIdx, fidx);
  hipLaunchKernelGGL(k_out, dim3(NROWS), dim3(256), 0, stream,
                     z, cb, fidx, out, lossSlots);
  hipLaunchKernelGGL(k_fin, dim3(1), dim3(256), 0, stream, lossSlots, out);
}